// Round 1
// baseline (1106.473 us; speedup 1.0000x reference)
//
#include <hip/hip_runtime.h>
#include <hip/hip_bf16.h>
#include <cstdint>

#define DIM 1536
#define NHEADS 12
#define HD 128
#define SEQ 3840

typedef float f32x4 __attribute__((ext_vector_type(4)));
typedef __bf16 bf16x8 __attribute__((ext_vector_type(8)));
typedef __bf16 bf16x4 __attribute__((ext_vector_type(4)));
typedef __bf16 bf16x2 __attribute__((ext_vector_type(2)));
typedef unsigned int u32;
typedef u32 u32x4 __attribute__((ext_vector_type(4)));

// ---------------- fp32 -> bf16 convert ----------------
__global__ __launch_bounds__(256) void cvt_bf16(const float* __restrict__ in,
                                                __bf16* __restrict__ out, int n4) {
    int i = blockIdx.x * 256 + threadIdx.x;
    if (i < n4) {
        f32x4 v = ((const f32x4*)in)[i];
        bf16x4 o;
        o[0] = (__bf16)v[0]; o[1] = (__bf16)v[1];
        o[2] = (__bf16)v[2]; o[3] = (__bf16)v[3];
        ((bf16x4*)out)[i] = o;
    }
}

// ---------------- GEMM: C[M][N] = A[M][K] * B[N][K]^T + bias ----------------
// m97-style 128x128 tile, BK=32, 4 waves (2x2), 4x4 16x16x32 frags per wave.
template <int OUTF32>
__global__ __launch_bounds__(256) void gemm_bt(
    const __bf16* __restrict__ A,
    const __bf16* __restrict__ B0, const __bf16* __restrict__ B1, const __bf16* __restrict__ B2,
    const float* __restrict__ bias0, const float* __restrict__ bias1, const float* __restrict__ bias2,
    void* __restrict__ C0v, void* __restrict__ C1v, void* __restrict__ C2v,
    int N, int K) {
    const __bf16* B = B0; const float* bias = bias0; void* Cv = C0v;
    if (blockIdx.z == 1) { B = B1; bias = bias1; Cv = C1v; }
    else if (blockIdx.z == 2) { B = B2; bias = bias2; Cv = C2v; }

    __shared__ __bf16 As[128 * 32];
    __shared__ __bf16 Bs[128 * 32];

    const int t = threadIdx.x;
    const int w = t >> 6;
    const int lane = t & 63;
    const int lr = lane & 15, lg = lane >> 4;
    const int wr = (w >> 1) * 64, wc = (w & 1) * 64;

    const long long rowA = (long long)blockIdx.y * 128 + (t >> 2);
    const long long rowB = (long long)blockIdx.x * 128 + (t >> 2);
    const int kcol = (t & 3) * 8;

    const __bf16* pa0 = A + rowA * K + kcol;
    const __bf16* pa1 = pa0 + 64LL * K;
    const __bf16* pb0 = B + rowB * K + kcol;
    const __bf16* pb1 = pb0 + 64LL * K;

    f32x4 acc[4][4] = {};

    u32x4 ra0 = *(const u32x4*)pa0;
    u32x4 ra1 = *(const u32x4*)pa1;
    u32x4 rb0 = *(const u32x4*)pb0;
    u32x4 rb1 = *(const u32x4*)pb1;

#pragma unroll 1
    for (int kk = 0; kk < K; kk += 32) {
        __syncthreads();
        *(u32x4*)(As + t * 8) = ra0;
        *(u32x4*)(As + 2048 + t * 8) = ra1;
        *(u32x4*)(Bs + t * 8) = rb0;
        *(u32x4*)(Bs + 2048 + t * 8) = rb1;
        __syncthreads();
        if (kk + 32 < K) {  // prefetch next K-step, overlaps with MFMA below
            ra0 = *(const u32x4*)(pa0 + kk + 32);
            ra1 = *(const u32x4*)(pa1 + kk + 32);
            rb0 = *(const u32x4*)(pb0 + kk + 32);
            rb1 = *(const u32x4*)(pb1 + kk + 32);
        }
        bf16x8 af[4], bfr[4];
#pragma unroll
        for (int m = 0; m < 4; m++)
            af[m] = *(const bf16x8*)(As + (wr + m * 16 + lr) * 32 + lg * 8);
#pragma unroll
        for (int n = 0; n < 4; n++)
            bfr[n] = *(const bf16x8*)(Bs + (wc + n * 16 + lr) * 32 + lg * 8);
#pragma unroll
        for (int m = 0; m < 4; m++)
#pragma unroll
            for (int n = 0; n < 4; n++)
                acc[m][n] = __builtin_amdgcn_mfma_f32_16x16x32_bf16(af[m], bfr[n], acc[m][n], 0, 0, 0);
    }

    const int cb = blockIdx.x * 128 + wc;
    const int rb_ = blockIdx.y * 128 + wr;
#pragma unroll
    for (int n = 0; n < 4; n++) {
        int col = cb + n * 16 + lr;
        float bv = bias[col];
#pragma unroll
        for (int m = 0; m < 4; m++) {
            int row0 = rb_ + m * 16 + lg * 4;
#pragma unroll
            for (int r = 0; r < 4; r++) {
                float v = acc[m][n][r] + bv;
                if (OUTF32) ((float*)Cv)[(long long)(row0 + r) * N + col] = v;
                else ((__bf16*)Cv)[(long long)(row0 + r) * N + col] = (__bf16)v;
            }
        }
    }
}

// ---------------- RMSNorm + RoPE, write [NH][SEQ][HD] ----------------
__global__ __launch_bounds__(256) void norm_rope(
    const __bf16* __restrict__ pre,   // [SEQ][DIM]
    const float* __restrict__ gvec,   // [DIM]
    const float* __restrict__ fcos,   // [1024][64]
    const float* __restrict__ fsin,
    __bf16* __restrict__ out) {       // [NH][SEQ][HD]
    const int s = blockIdx.x;
    const int t = threadIdx.x;
    float a[3], b[3];
    float ss = 0.f;
#pragma unroll
    for (int j = 0; j < 3; j++) {
        int p = t + 256 * j;
        bf16x2 v = *(const bf16x2*)(pre + (size_t)s * DIM + 2 * p);
        a[j] = (float)v[0]; b[j] = (float)v[1];
        ss += a[j] * a[j] + b[j] * b[j];
    }
    for (int off = 32; off; off >>= 1) ss += __shfl_down(ss, off);
    __shared__ float red[4];
    if ((t & 63) == 0) red[t >> 6] = ss;
    __syncthreads();
    float mean = (red[0] + red[1] + red[2] + red[3]) * (1.f / DIM);
    float rms = rsqrtf(mean + 1e-6f);
    const int fi = s / 640, hi2 = (s % 640) >> 5, wi = s & 31;
#pragma unroll
    for (int j = 0; j < 3; j++) {
        int p = t + 256 * j;
        int c = p & 63;
        int pos = (c < 22) ? fi : ((c < 43) ? hi2 : wi);
        float fc = fcos[pos * 64 + c];
        float fs = fsin[pos * 64 + c];
        float av = a[j] * rms * gvec[2 * p];
        float bv = b[j] * rms * gvec[2 * p + 1];
        float orr = av * fc - bv * fs;
        float oi = av * fs + bv * fc;
        int hh = p >> 6;
        bf16x2 o; o[0] = (__bf16)orr; o[1] = (__bf16)oi;
        *(bf16x2*)(out + ((size_t)hh * SEQ + s) * HD + 2 * c) = o;
    }
}

// ---------------- transpose [SEQ][DIM] -> [DIM][SEQ] ----------------
__global__ __launch_bounds__(256) void transpose_bf16(
    const __bf16* __restrict__ in, __bf16* __restrict__ out) {
    __shared__ __bf16 tile[64][68];
    const int t = threadIdx.x;
    const int sb = blockIdx.x * 64, cb = blockIdx.y * 64;
    const int tx = t & 15, ty = t >> 4;
#pragma unroll
    for (int i = 0; i < 4; i++) {
        int r = ty + i * 16;
        bf16x4 v = *(const bf16x4*)(in + (size_t)(sb + r) * DIM + cb + tx * 4);
        *(bf16x4*)&tile[r][tx * 4] = v;
    }
    __syncthreads();
#pragma unroll
    for (int i = 0; i < 4; i++) {
        int c = ty + i * 16;
        bf16x4 v;
        v[0] = tile[tx * 4 + 0][c]; v[1] = tile[tx * 4 + 1][c];
        v[2] = tile[tx * 4 + 2][c]; v[3] = tile[tx * 4 + 3][c];
        *(bf16x4*)(out + (size_t)(cb + c) * SEQ + sb + tx * 4) = v;
    }
}

// ---------------- flash attention ----------------
// grid (NH, SEQ/64); 4 waves/block, 16 q-rows/wave, KV blocks of 32.
// Swapped QK^T and swapped PV so softmax state + O acc are indexed by q=lane&15.
__global__ __launch_bounds__(256) void attn(
    const __bf16* __restrict__ Q,    // [NH][SEQ][HD]
    const __bf16* __restrict__ Kk,   // [NH][SEQ][HD]
    const __bf16* __restrict__ Vt,   // [NH][HD][SEQ]
    __bf16* __restrict__ O) {        // [SEQ][DIM]
    const int h = blockIdx.x;
    const int t = threadIdx.x;
    const int wv = t >> 6, lane = t & 63;
    const int q0 = blockIdx.y * 64 + wv * 16;
    const int lq = lane & 15, g = lane >> 4;

    const __bf16* Qh = Q + (size_t)h * SEQ * HD;
    const __bf16* Kh = Kk + (size_t)h * SEQ * HD;
    const __bf16* Vh = Vt + (size_t)h * HD * SEQ;

    bf16x8 qf[4];
#pragma unroll
    for (int c = 0; c < 4; c++)
        qf[c] = *(const bf16x8*)(Qh + (size_t)(q0 + lq) * HD + c * 32 + g * 8);

    f32x4 acc[8] = {};
    float m = -1e30f, l = 0.f;
    const float SCL2 = 0.1275365308119098f;  // (1/sqrt(128)) * log2(e)

#pragma unroll 1
    for (int kv = 0; kv < SEQ; kv += 32) {
        f32x4 s0 = {0.f, 0.f, 0.f, 0.f}, s1 = {0.f, 0.f, 0.f, 0.f};
        const __bf16* kp = Kh + (size_t)(kv + lq) * HD + g * 8;
#pragma unroll
        for (int c = 0; c < 4; c++) {
            bf16x8 k0 = *(const bf16x8*)(kp + c * 32);
            bf16x8 k1 = *(const bf16x8*)(kp + 16 * HD + c * 32);
            s0 = __builtin_amdgcn_mfma_f32_16x16x32_bf16(k0, qf[c], s0, 0, 0, 0);
            s1 = __builtin_amdgcn_mfma_f32_16x16x32_bf16(k1, qf[c], s1, 0, 0, 0);
        }
        float pm = fmaxf(fmaxf(fmaxf(s0[0], s0[1]), fmaxf(s0[2], s0[3])),
                         fmaxf(fmaxf(s1[0], s1[1]), fmaxf(s1[2], s1[3])));
        pm = fmaxf(pm, __shfl_xor(pm, 16));
        pm = fmaxf(pm, __shfl_xor(pm, 32));
        float mn = fmaxf(m, pm);
        float al = exp2f(SCL2 * (m - mn));
        m = mn;
        float p[8]; float ls = 0.f;
#pragma unroll
        for (int r = 0; r < 4; r++) { p[r] = exp2f(SCL2 * (s0[r] - m)); ls += p[r]; }
#pragma unroll
        for (int r = 0; r < 4; r++) { p[4 + r] = exp2f(SCL2 * (s1[r] - m)); ls += p[4 + r]; }
        ls += __shfl_xor(ls, 16);
        ls += __shfl_xor(ls, 32);
        l = l * al + ls;
        bf16x8 pa;
#pragma unroll
        for (int i = 0; i < 8; i++) pa[i] = (__bf16)p[i];
#pragma unroll
        for (int dt = 0; dt < 8; dt++) {
#pragma unroll
            for (int r = 0; r < 4; r++) acc[dt][r] *= al;
            const __bf16* vp = Vh + (size_t)(dt * 16 + lq) * SEQ + kv + g * 4;
            bf16x4 v0 = *(const bf16x4*)vp;
            bf16x4 v1 = *(const bf16x4*)(vp + 16);
            bf16x8 vf = __builtin_shufflevector(v0, v1, 0, 1, 2, 3, 4, 5, 6, 7);
            acc[dt] = __builtin_amdgcn_mfma_f32_16x16x32_bf16(vf, pa, acc[dt], 0, 0, 0);
        }
    }
    float inv = 1.f / l;
#pragma unroll
    for (int dt = 0; dt < 8; dt++) {
        bf16x4 o;
#pragma unroll
        for (int r = 0; r < 4; r++) o[r] = (__bf16)(acc[dt][r] * inv);
        *(bf16x4*)(O + (size_t)(q0 + lq) * DIM + h * HD + dt * 16 + g * 4) = o;
    }
}

extern "C" void kernel_launch(void* const* d_in, const int* in_sizes, int n_in,
                              void* d_out, int out_size, void* d_ws, size_t ws_size,
                              hipStream_t stream) {
    const float* x = (const float*)d_in[0];
    const float* Wq = (const float*)d_in[1];
    const float* bq = (const float*)d_in[2];
    const float* Wk = (const float*)d_in[3];
    const float* bk = (const float*)d_in[4];
    const float* Wv = (const float*)d_in[5];
    const float* bv = (const float*)d_in[6];
    const float* Wo = (const float*)d_in[7];
    const float* bo = (const float*)d_in[8];
    const float* gq = (const float*)d_in[9];
    const float* gk = (const float*)d_in[10];
    const float* fcos = (const float*)d_in[11];
    const float* fsin = (const float*)d_in[12];
    float* out = (float*)d_out;

    char* ws = (char*)d_ws;
    const size_t SZ_SD = (size_t)SEQ * DIM * 2;   // 11.25 MB
    const size_t SZ_W = (size_t)DIM * DIM * 2;    // 4.5 MB
    __bf16* xb   = (__bf16*)ws;            ws += SZ_SD;   // also reused as Qb
    __bf16* Wqb  = (__bf16*)ws;            ws += SZ_W;
    __bf16* Wkb  = (__bf16*)ws;            ws += SZ_W;
    __bf16* Wvb  = (__bf16*)ws;            ws += SZ_W;
    __bf16* Wob  = (__bf16*)ws;            ws += SZ_W;
    __bf16* qpre = (__bf16*)ws;            ws += SZ_SD;   // also reused as ob
    __bf16* kpre = (__bf16*)ws;            ws += SZ_SD;
    __bf16* vpre = (__bf16*)ws;            ws += SZ_SD;
    __bf16* Kb   = (__bf16*)ws;            ws += SZ_SD;
    __bf16* Vtb  = (__bf16*)ws;            ws += SZ_SD;
    __bf16* Qb = xb;     // xb dead after QKV GEMM
    __bf16* ob = qpre;   // qpre dead after norm_rope(q)

    int n4 = SEQ * DIM / 4;
    cvt_bf16<<<(n4 + 255) / 256, 256, 0, stream>>>(x, xb, n4);
    n4 = DIM * DIM / 4;
    cvt_bf16<<<(n4 + 255) / 256, 256, 0, stream>>>(Wq, Wqb, n4);
    cvt_bf16<<<(n4 + 255) / 256, 256, 0, stream>>>(Wk, Wkb, n4);
    cvt_bf16<<<(n4 + 255) / 256, 256, 0, stream>>>(Wv, Wvb, n4);
    cvt_bf16<<<(n4 + 255) / 256, 256, 0, stream>>>(Wo, Wob, n4);

    gemm_bt<0><<<dim3(DIM / 128, SEQ / 128, 3), 256, 0, stream>>>(
        xb, Wqb, Wkb, Wvb, bq, bk, bv, qpre, kpre, vpre, DIM, DIM);

    norm_rope<<<SEQ, 256, 0, stream>>>(qpre, gq, fcos, fsin, Qb);
    norm_rope<<<SEQ, 256, 0, stream>>>(kpre, gk, fcos, fsin, Kb);
    transpose_bf16<<<dim3(SEQ / 64, DIM / 64), 256, 0, stream>>>(vpre, Vtb);

    attn<<<dim3(NHEADS, SEQ / 64), 256, 0, stream>>>(Qb, Kb, Vtb, ob);

    gemm_bt<1><<<dim3(DIM / 128, SEQ / 128, 1), 256, 0, stream>>>(
        ob, Wob, Wob, Wob, bo, bo, bo, out, out, out, DIM, DIM);
}

// Round 2
// 482.762 us; speedup vs baseline: 2.2920x; 2.2920x over previous
//
#include <hip/hip_runtime.h>
#include <hip/hip_bf16.h>
#include <cstdint>

#define DIM 1536
#define NHEADS 12
#define HD 128
#define SEQ 3840

typedef float f32x4 __attribute__((ext_vector_type(4)));
typedef __bf16 bf16x8 __attribute__((ext_vector_type(8)));
typedef __bf16 bf16x4 __attribute__((ext_vector_type(4)));
typedef __bf16 bf16x2 __attribute__((ext_vector_type(2)));
typedef unsigned int u32;
typedef u32 u32x4 __attribute__((ext_vector_type(4)));

// ---------------- fp32 -> bf16 convert ----------------
__global__ __launch_bounds__(256) void cvt_bf16(const float* __restrict__ in,
                                                __bf16* __restrict__ out, int n4) {
    int i = blockIdx.x * 256 + threadIdx.x;
    if (i < n4) {
        f32x4 v = ((const f32x4*)in)[i];
        bf16x4 o;
        o[0] = (__bf16)v[0]; o[1] = (__bf16)v[1];
        o[2] = (__bf16)v[2]; o[3] = (__bf16)v[3];
        ((bf16x4*)out)[i] = o;
    }
}

// ---------------- GEMM: C[M][N] = A[M][K] * B[N][K]^T + bias ----------------
template <int OUTF32>
__global__ __launch_bounds__(256) void gemm_bt(
    const __bf16* __restrict__ A,
    const __bf16* __restrict__ B0, const __bf16* __restrict__ B1, const __bf16* __restrict__ B2,
    const float* __restrict__ bias0, const float* __restrict__ bias1, const float* __restrict__ bias2,
    void* __restrict__ C0v, void* __restrict__ C1v, void* __restrict__ C2v,
    int N, int K) {
    const __bf16* B = B0; const float* bias = bias0; void* Cv = C0v;
    if (blockIdx.z == 1) { B = B1; bias = bias1; Cv = C1v; }
    else if (blockIdx.z == 2) { B = B2; bias = bias2; Cv = C2v; }

    __shared__ __bf16 As[128 * 32];
    __shared__ __bf16 Bs[128 * 32];

    const int t = threadIdx.x;
    const int w = t >> 6;
    const int lane = t & 63;
    const int lr = lane & 15, lg = lane >> 4;
    const int wr = (w >> 1) * 64, wc = (w & 1) * 64;

    const long long rowA = (long long)blockIdx.y * 128 + (t >> 2);
    const long long rowB = (long long)blockIdx.x * 128 + (t >> 2);
    const int kcol = (t & 3) * 8;

    const __bf16* pa0 = A + rowA * K + kcol;
    const __bf16* pa1 = pa0 + 64LL * K;
    const __bf16* pb0 = B + rowB * K + kcol;
    const __bf16* pb1 = pb0 + 64LL * K;

    f32x4 acc[4][4] = {};

    u32x4 ra0 = *(const u32x4*)pa0;
    u32x4 ra1 = *(const u32x4*)pa1;
    u32x4 rb0 = *(const u32x4*)pb0;
    u32x4 rb1 = *(const u32x4*)pb1;

#pragma unroll 1
    for (int kk = 0; kk < K; kk += 32) {
        __syncthreads();
        *(u32x4*)(As + t * 8) = ra0;
        *(u32x4*)(As + 2048 + t * 8) = ra1;
        *(u32x4*)(Bs + t * 8) = rb0;
        *(u32x4*)(Bs + 2048 + t * 8) = rb1;
        __syncthreads();
        if (kk + 32 < K) {
            ra0 = *(const u32x4*)(pa0 + kk + 32);
            ra1 = *(const u32x4*)(pa1 + kk + 32);
            rb0 = *(const u32x4*)(pb0 + kk + 32);
            rb1 = *(const u32x4*)(pb1 + kk + 32);
        }
        bf16x8 af[4], bfr[4];
#pragma unroll
        for (int m = 0; m < 4; m++)
            af[m] = *(const bf16x8*)(As + (wr + m * 16 + lr) * 32 + lg * 8);
#pragma unroll
        for (int n = 0; n < 4; n++)
            bfr[n] = *(const bf16x8*)(Bs + (wc + n * 16 + lr) * 32 + lg * 8);
#pragma unroll
        for (int m = 0; m < 4; m++)
#pragma unroll
            for (int n = 0; n < 4; n++)
                acc[m][n] = __builtin_amdgcn_mfma_f32_16x16x32_bf16(af[m], bfr[n], acc[m][n], 0, 0, 0);
    }

    const int cb = blockIdx.x * 128 + wc;
    const int rb_ = blockIdx.y * 128 + wr;
#pragma unroll
    for (int n = 0; n < 4; n++) {
        int col = cb + n * 16 + lr;
        float bv = bias[col];
#pragma unroll
        for (int m = 0; m < 4; m++) {
            int row0 = rb_ + m * 16 + lg * 4;
#pragma unroll
            for (int r = 0; r < 4; r++) {
                float v = acc[m][n][r] + bv;
                if (OUTF32) ((float*)Cv)[(long long)(row0 + r) * N + col] = v;
                else ((__bf16*)Cv)[(long long)(row0 + r) * N + col] = (__bf16)v;
            }
        }
    }
}

// ---------------- RMSNorm + RoPE, write [NH][SEQ][HD] ----------------
__global__ __launch_bounds__(256) void norm_rope(
    const __bf16* __restrict__ pre,   // [SEQ][DIM]
    const float* __restrict__ gvec,   // [DIM]
    const float* __restrict__ fcos,   // [1024][64]
    const float* __restrict__ fsin,
    __bf16* __restrict__ out) {       // [NH][SEQ][HD]
    const int s = blockIdx.x;
    const int t = threadIdx.x;
    float a[3], b[3];
    float ss = 0.f;
#pragma unroll
    for (int j = 0; j < 3; j++) {
        int p = t + 256 * j;
        bf16x2 v = *(const bf16x2*)(pre + (size_t)s * DIM + 2 * p);
        a[j] = (float)v[0]; b[j] = (float)v[1];
        ss += a[j] * a[j] + b[j] * b[j];
    }
    for (int off = 32; off; off >>= 1) ss += __shfl_down(ss, off);
    __shared__ float red[4];
    if ((t & 63) == 0) red[t >> 6] = ss;
    __syncthreads();
    float mean = (red[0] + red[1] + red[2] + red[3]) * (1.f / DIM);
    float rms = rsqrtf(mean + 1e-6f);
    const int fi = s / 640, hi2 = (s % 640) >> 5, wi = s & 31;
#pragma unroll
    for (int j = 0; j < 3; j++) {
        int p = t + 256 * j;
        int c = p & 63;
        int pos = (c < 22) ? fi : ((c < 43) ? hi2 : wi);
        float fc = fcos[pos * 64 + c];
        float fs = fsin[pos * 64 + c];
        float av = a[j] * rms * gvec[2 * p];
        float bv = b[j] * rms * gvec[2 * p + 1];
        float orr = av * fc - bv * fs;
        float oi = av * fs + bv * fc;
        int hh = p >> 6;
        bf16x2 o; o[0] = (__bf16)orr; o[1] = (__bf16)oi;
        *(bf16x2*)(out + ((size_t)hh * SEQ + s) * HD + 2 * c) = o;
    }
}

// ---------------- transpose [SEQ][DIM] -> [DIM][SEQ] with kv-slot permute ----
// Output column (kv) permuted within each 32-block so the attn PV A-fragment
// is one contiguous 16B read: stored g*8+r <- kv g*4+r, stored g*8+4+r <- kv 16+g*4+r.
__global__ __launch_bounds__(256) void transpose_bf16(
    const __bf16* __restrict__ in, __bf16* __restrict__ out) {
    __shared__ __bf16 tile[64][68];
    const int t = threadIdx.x;
    const int sb = blockIdx.x * 64, cb = blockIdx.y * 64;
    const int tx = t & 15, ty = t >> 4;
#pragma unroll
    for (int i = 0; i < 4; i++) {
        int r = ty + i * 16;
        bf16x4 v = *(const bf16x4*)(in + (size_t)(sb + r) * DIM + cb + tx * 4);
        *(bf16x4*)&tile[r][tx * 4] = v;
    }
    __syncthreads();
    // permuted output s-position for this thread's 4-column group
    int s0 = sb + tx * 4;
    int j = (s0 >> 2) & 7;
    int u = (j < 4) ? (j << 1) : ((j << 1) - 7);
    int sp = (s0 & ~31) + (u << 2);
#pragma unroll
    for (int i = 0; i < 4; i++) {
        int c = ty + i * 16;
        bf16x4 v;
        v[0] = tile[tx * 4 + 0][c]; v[1] = tile[tx * 4 + 1][c];
        v[2] = tile[tx * 4 + 2][c]; v[3] = tile[tx * 4 + 3][c];
        *(bf16x4*)(out + (size_t)(cb + c) * SEQ + sp) = v;
    }
}

// ---------------- flash attention ----------------
// grid (NH, SEQ/32); one independent 64-lane wave per block, 32 q-rows/wave.
// Swapped QK^T and swapped PV; softmax state + O acc indexed by q=lane&15.
__global__ __launch_bounds__(64) void attn(
    const __bf16* __restrict__ Q,    // [NH][SEQ][HD]
    const __bf16* __restrict__ Kk,   // [NH][SEQ][HD]
    const __bf16* __restrict__ Vp,   // [NH][HD][SEQ] (kv-permuted in 32-blocks)
    __bf16* __restrict__ O) {        // [SEQ][DIM]
    const int h = blockIdx.x;
    const int lane = threadIdx.x;
    const int q0 = blockIdx.y * 32;
    const int lq = lane & 15, g = lane >> 4;

    const __bf16* Qh = Q + (size_t)h * SEQ * HD;
    const __bf16* Kh = Kk + (size_t)h * SEQ * HD;
    const __bf16* Vh = Vp + (size_t)h * HD * SEQ;

    bf16x8 qf[2][4];
#pragma unroll
    for (int qg = 0; qg < 2; qg++)
#pragma unroll
        for (int c = 0; c < 4; c++)
            qf[qg][c] = *(const bf16x8*)(Qh + (size_t)(q0 + qg * 16 + lq) * HD + c * 32 + g * 8);

    f32x4 acc[8][2] = {};
    float m[2] = {-1e30f, -1e30f}, l[2] = {0.f, 0.f};
    const float SCL2 = 0.1275365308119098f;   // (1/sqrt(128)) * log2(e)
    const float THR_RAW = 90.50966799187809f; // 8 nats / (1/sqrt(128))

#pragma unroll 1
    for (int kv = 0; kv < SEQ; kv += 32) {
        // V fragments first (consumed last) so their latency hides under QK+softmax
        bf16x8 vf[8];
#pragma unroll
        for (int dt = 0; dt < 8; dt++)
            vf[dt] = *(const bf16x8*)(Vh + (size_t)(dt * 16 + lq) * SEQ + kv + g * 8);

        bf16x8 kf[2][4];
#pragma unroll
        for (int kvg = 0; kvg < 2; kvg++)
#pragma unroll
            for (int c = 0; c < 4; c++)
                kf[kvg][c] = *(const bf16x8*)(Kh + (size_t)(kv + kvg * 16 + lq) * HD + c * 32 + g * 8);

        f32x4 sc[2][2] = {};
#pragma unroll
        for (int c = 0; c < 4; c++)
#pragma unroll
            for (int kvg = 0; kvg < 2; kvg++)
#pragma unroll
                for (int qg = 0; qg < 2; qg++)
                    sc[kvg][qg] = __builtin_amdgcn_mfma_f32_16x16x32_bf16(kf[kvg][c], qf[qg][c], sc[kvg][qg], 0, 0, 0);

        bf16x8 pa[2];
#pragma unroll
        for (int qg = 0; qg < 2; qg++) {
            float pm = fmaxf(fmaxf(fmaxf(sc[0][qg][0], sc[0][qg][1]), fmaxf(sc[0][qg][2], sc[0][qg][3])),
                             fmaxf(fmaxf(sc[1][qg][0], sc[1][qg][1]), fmaxf(sc[1][qg][2], sc[1][qg][3])));
            pm = fmaxf(pm, __shfl_xor(pm, 16));
            pm = fmaxf(pm, __shfl_xor(pm, 32));
            if (!__all(pm <= m[qg] + THR_RAW)) {   // defer-max: rescale only when max grows
                float mn = fmaxf(m[qg], pm);
                float al = __builtin_amdgcn_exp2f(SCL2 * (m[qg] - mn));
                m[qg] = mn;
                l[qg] *= al;
#pragma unroll
                for (int dt = 0; dt < 8; dt++)
#pragma unroll
                    for (int r = 0; r < 4; r++) acc[dt][qg][r] *= al;
            }
            float ms = SCL2 * m[qg];
            float p[8], ls = 0.f;
#pragma unroll
            for (int r = 0; r < 4; r++) { p[r] = __builtin_amdgcn_exp2f(SCL2 * sc[0][qg][r] - ms); ls += p[r]; }
#pragma unroll
            for (int r = 0; r < 4; r++) { p[4 + r] = __builtin_amdgcn_exp2f(SCL2 * sc[1][qg][r] - ms); ls += p[4 + r]; }
            ls += __shfl_xor(ls, 16);
            ls += __shfl_xor(ls, 32);
            l[qg] += ls;
#pragma unroll
            for (int i = 0; i < 8; i++) pa[qg][i] = (__bf16)p[i];
        }

#pragma unroll
        for (int dt = 0; dt < 8; dt++)
#pragma unroll
            for (int qg = 0; qg < 2; qg++)
                acc[dt][qg] = __builtin_amdgcn_mfma_f32_16x16x32_bf16(vf[dt], pa[qg], acc[dt][qg], 0, 0, 0);
    }

#pragma unroll
    for (int qg = 0; qg < 2; qg++) {
        float inv = 1.f / l[qg];
#pragma unroll
        for (int dt = 0; dt < 8; dt++) {
            bf16x4 o;
#pragma unroll
            for (int r = 0; r < 4; r++) o[r] = (__bf16)(acc[dt][qg][r] * inv);
            *(bf16x4*)(O + (size_t)(q0 + qg * 16 + lq) * DIM + h * HD + dt * 16 + g * 4) = o;
        }
    }
}

extern "C" void kernel_launch(void* const* d_in, const int* in_sizes, int n_in,
                              void* d_out, int out_size, void* d_ws, size_t ws_size,
                              hipStream_t stream) {
    const float* x = (const float*)d_in[0];
    const float* Wq = (const float*)d_in[1];
    const float* bq = (const float*)d_in[2];
    const float* Wk = (const float*)d_in[3];
    const float* bk = (const float*)d_in[4];
    const float* Wv = (const float*)d_in[5];
    const float* bv = (const float*)d_in[6];
    const float* Wo = (const float*)d_in[7];
    const float* bo = (const float*)d_in[8];
    const float* gq = (const float*)d_in[9];
    const float* gk = (const float*)d_in[10];
    const float* fcos = (const float*)d_in[11];
    const float* fsin = (const float*)d_in[12];
    float* out = (float*)d_out;

    char* ws = (char*)d_ws;
    const size_t SZ_SD = (size_t)SEQ * DIM * 2;   // 11.25 MB
    const size_t SZ_W = (size_t)DIM * DIM * 2;    // 4.5 MB
    __bf16* xb   = (__bf16*)ws;            ws += SZ_SD;   // also reused as Qb
    __bf16* Wqb  = (__bf16*)ws;            ws += SZ_W;
    __bf16* Wkb  = (__bf16*)ws;            ws += SZ_W;
    __bf16* Wvb  = (__bf16*)ws;            ws += SZ_W;
    __bf16* Wob  = (__bf16*)ws;            ws += SZ_W;
    __bf16* qpre = (__bf16*)ws;            ws += SZ_SD;   // also reused as ob
    __bf16* kpre = (__bf16*)ws;            ws += SZ_SD;
    __bf16* vpre = (__bf16*)ws;            ws += SZ_SD;
    __bf16* Kb   = (__bf16*)ws;            ws += SZ_SD;
    __bf16* Vtb  = (__bf16*)ws;            ws += SZ_SD;
    __bf16* Qb = xb;     // xb dead after QKV GEMM
    __bf16* ob = qpre;   // qpre dead after norm_rope(q)

    int n4 = SEQ * DIM / 4;
    cvt_bf16<<<(n4 + 255) / 256, 256, 0, stream>>>(x, xb, n4);
    n4 = DIM * DIM / 4;
    cvt_bf16<<<(n4 + 255) / 256, 256, 0, stream>>>(Wq, Wqb, n4);
    cvt_bf16<<<(n4 + 255) / 256, 256, 0, stream>>>(Wk, Wkb, n4);
    cvt_bf16<<<(n4 + 255) / 256, 256, 0, stream>>>(Wv, Wvb, n4);
    cvt_bf16<<<(n4 + 255) / 256, 256, 0, stream>>>(Wo, Wob, n4);

    gemm_bt<0><<<dim3(DIM / 128, SEQ / 128, 3), 256, 0, stream>>>(
        xb, Wqb, Wkb, Wvb, bq, bk, bv, qpre, kpre, vpre, DIM, DIM);

    norm_rope<<<SEQ, 256, 0, stream>>>(qpre, gq, fcos, fsin, Qb);
    norm_rope<<<SEQ, 256, 0, stream>>>(kpre, gk, fcos, fsin, Kb);
    transpose_bf16<<<dim3(SEQ / 64, DIM / 64), 256, 0, stream>>>(vpre, Vtb);

    attn<<<dim3(NHEADS, SEQ / 32), 64, 0, stream>>>(Qb, Kb, Vtb, ob);

    gemm_bt<1><<<dim3(DIM / 128, SEQ / 128, 1), 256, 0, stream>>>(
        ob, Wob, Wob, Wob, bo, bo, bo, out, out, out, DIM, DIM);
}